// Round 23
// baseline (235.213 us; speedup 1.0000x reference)
//
#include <hip/hip_runtime.h>
#include <hip/hip_bf16.h>
#include <math.h>

#define BB 16
#define CC 512
#define DD 64
#define NN 4096
#define EPSV 1e-6f
#define NCH 8   // split-K chunks for KX

typedef __attribute__((ext_vector_type(8))) short short8;
typedef __attribute__((ext_vector_type(4))) short s16x4;
typedef __attribute__((ext_vector_type(4))) float f32x4;

// fast softplus: hardware v_exp_f32 / v_log_f32 (arg of log in (1,2])
__device__ __forceinline__ float softplus_f(float v) {
    return fmaxf(v, 0.0f) + __logf(1.0f + __expf(-fabsf(v)));
}
__device__ __forceinline__ short bf16s(float f) {
    __hip_bfloat16 h = __float2bfloat16(f);
    return __builtin_bit_cast(short, h);
}
__device__ __forceinline__ float sbf16(short s) {
    return __bfloat162float(__builtin_bit_cast(__hip_bfloat16, s));
}

// ---- prep: Wcat bf16 [128][512] (blocks 0-255), zero Ksum (block 256) ----
__global__ __launch_bounds__(256) void k_prep(const float* __restrict__ Wq,
                                              const float* __restrict__ Wk,
                                              __hip_bfloat16* __restrict__ Wcat,
                                              float* __restrict__ Ksum) {
    int blk = blockIdx.x;
    if (blk < 256) {
        int i = blk * 256 + threadIdx.x;
        int j = i >> 9, c = i & 511;
        float v = (j < DD) ? Wq[j * CC + c] : Wk[(j - DD) * CC + c];
        Wcat[i] = __float2bfloat16(v);
    } else {
        f32x4 z = {0.f, 0.f, 0.f, 0.f};
        reinterpret_cast<f32x4*>(Ksum)[threadIdx.x] = z;  // 1024 floats
    }
}

// ---- Q/K projection via MFMA (measured-best r6 path, relaxed barrier).
//      Also emits xb16[b][c][n] (bf16 copy of x). Fused Ksum.
//      Qb[b][n][d] bf16 ; Kb[b][m][n] bf16 ----
__global__ __launch_bounds__(256) void k_proj(const float* __restrict__ x,
                                              const __hip_bfloat16* __restrict__ Wcat,
                                              const float* __restrict__ bq,
                                              const float* __restrict__ bk,
                                              __hip_bfloat16* __restrict__ Qb,
                                              __hip_bfloat16* __restrict__ Kb,
                                              __hip_bfloat16* __restrict__ xb16,
                                              float* __restrict__ Ksum) {
    __shared__ unsigned short xs[2][32][132];
    __shared__ unsigned short ws[2][128][40];

    int b = blockIdx.y;
    int n_blk = blockIdx.x * 128;
    int t = threadIdx.x;
    int wave = t >> 6, lane = t & 63;
    int nwl = wave * 32;                    // wave's local n base
    int n_wave = n_blk + nwl;
    int l16 = lane & 15, g = lane >> 4;

    int sv = t & 31;
    int sc = t >> 5;
    int wj = t >> 1;
    int wh = t & 1;

    const float* xb = x + (size_t)b * CC * NN + n_blk + sv * 4;
    unsigned short* xg = reinterpret_cast<unsigned short*>(xb16)
                         + (size_t)b * CC * NN + n_blk + sv * 4;
    const unsigned short* wg = reinterpret_cast<const unsigned short*>(Wcat)
                               + (size_t)wj * 512 + wh * 16;

    f32x4 xr[4];
    s16x4 wr[4];

    auto loadx = [&](int c0) {
#pragma unroll
        for (int i = 0; i < 4; ++i)
            xr[i] = *reinterpret_cast<const f32x4*>(xb + (size_t)(c0 + sc + i * 8) * NN);
    };
    auto loadw = [&](int c0) {
#pragma unroll
        for (int k = 0; k < 4; ++k)
            wr[k] = *reinterpret_cast<const s16x4*>(wg + c0 + k * 4);
    };
    auto writex = [&](int bi, int c0) {
#pragma unroll
        for (int i = 0; i < 4; ++i) {
            s16x4 pv;
#pragma unroll
            for (int j = 0; j < 4; ++j) pv[j] = bf16s(xr[i][j]);
            *reinterpret_cast<s16x4*>(&xs[bi][sc + i * 8][sv * 4]) = pv;
            *reinterpret_cast<s16x4*>(&xg[(size_t)(c0 + sc + i * 8) * NN]) = pv;
        }
    };
    auto writew = [&](int bi) {
#pragma unroll
        for (int k = 0; k < 4; ++k)
            *reinterpret_cast<s16x4*>(&ws[bi][wj][wh * 16 + k * 4]) = wr[k];
    };

    f32x4 accQ[2][4] = {};
    f32x4 accK[4][2] = {};

    loadx(0); loadw(0);
    writex(0, 0); writew(0);

    for (int ck = 0; ck < 16; ++ck) {
        int cur = ck & 1;
        if (ck < 15) { loadx((ck + 1) * 32); loadw((ck + 1) * 32); }
        asm volatile("s_waitcnt lgkmcnt(0)" ::: "memory");
        __builtin_amdgcn_s_barrier();
        short8 xf[2], wf[8];
#pragma unroll
        for (int nf = 0; nf < 2; ++nf) {
            short8 v;
#pragma unroll
            for (int e = 0; e < 8; ++e)
                v[e] = (short)xs[cur][g * 8 + e][nwl + nf * 16 + l16];
            xf[nf] = v;
        }
#pragma unroll
        for (int jf = 0; jf < 8; ++jf)
            wf[jf] = *reinterpret_cast<const short8*>(&ws[cur][jf * 16 + l16][g * 8]);
#pragma unroll
        for (int nf = 0; nf < 2; ++nf)
#pragma unroll
            for (int jf = 0; jf < 4; ++jf)
                accQ[nf][jf] = __builtin_amdgcn_mfma_f32_16x16x32_bf16(xf[nf], wf[jf], accQ[nf][jf], 0, 0, 0);
#pragma unroll
        for (int jf = 0; jf < 4; ++jf)
#pragma unroll
            for (int nf = 0; nf < 2; ++nf)
                accK[jf][nf] = __builtin_amdgcn_mfma_f32_16x16x32_bf16(wf[4 + jf], xf[nf], accK[jf][nf], 0, 0, 0);
        if (ck < 15) { writex(cur ^ 1, (ck + 1) * 32); writew(cur ^ 1); }
    }

#pragma unroll
    for (int nf = 0; nf < 2; ++nf)
#pragma unroll
        for (int jf = 0; jf < 4; ++jf)
#pragma unroll
            for (int r = 0; r < 4; ++r) {
                int n = n_wave + nf * 16 + 4 * g + r;
                int j = jf * 16 + l16;
                float v = softplus_f(accQ[nf][jf][r] + bq[j]);
                Qb[((size_t)b * NN + n) * DD + j] = __float2bfloat16(v);
            }
#pragma unroll
    for (int jf = 0; jf < 4; ++jf)
#pragma unroll
        for (int r = 0; r < 4; ++r) {
            int m = jf * 16 + 4 * g + r;
            float s = 0.f;
#pragma unroll
            for (int nf = 0; nf < 2; ++nf) {
                int n = n_wave + nf * 16 + l16;
                float v = softplus_f(accK[jf][nf][r] + bk[m]);
                Kb[((size_t)b * DD + m) * NN + n] = __float2bfloat16(v);
                s += v;
            }
            s += __shfl_xor(s, 1, 64);
            s += __shfl_xor(s, 2, 64);
            s += __shfl_xor(s, 4, 64);
            s += __shfl_xor(s, 8, 64);
            if (l16 == 0) atomicAdd(&Ksum[b * DD + m], s);
        }
}

// ---- KXpb[ch][b][m][c] (bf16) = sum_{nn in chunk} Kb[m][nn]*xb16[c][nn]
//      (MFMA, no LDS, no atomics, bf16 partials) ----
__global__ __launch_bounds__(256) void k_kx(const __hip_bfloat16* __restrict__ Kb,
                                            const __hip_bfloat16* __restrict__ xb16,
                                            unsigned short* __restrict__ KXpb) {
    int b = blockIdx.z;
    int ch = blockIdx.y;                      // 8 n-chunks of 512
    int n0 = ch * 512;
    int c0 = blockIdx.x * 256;                // 2 c-halves
    int wave = threadIdx.x >> 6, lane = threadIdx.x & 63;
    int cw = c0 + wave * 64;                  // wave owns 64 c-cols
    int l16 = lane & 15, g = lane >> 4;

    f32x4 acc[4][4] = {};                     // [mi][cj]
    const __hip_bfloat16* kp = Kb + (size_t)b * DD * NN;
    const __hip_bfloat16* xp = xb16 + (size_t)b * CC * NN;

#pragma unroll 4
    for (int ks = 0; ks < 16; ++ks) {         // 512 n in steps of 32
        int nk = n0 + ks * 32 + g * 8;
        short8 af[4], bf[4];
#pragma unroll
        for (int mi = 0; mi < 4; ++mi)
            af[mi] = *reinterpret_cast<const short8*>(kp + (size_t)(mi * 16 + l16) * NN + nk);
#pragma unroll
        for (int cj = 0; cj < 4; ++cj)
            bf[cj] = *reinterpret_cast<const short8*>(xp + (size_t)(cw + cj * 16 + l16) * NN + nk);
#pragma unroll
        for (int mi = 0; mi < 4; ++mi)
#pragma unroll
            for (int cj = 0; cj < 4; ++cj)
                acc[mi][cj] = __builtin_amdgcn_mfma_f32_16x16x32_bf16(af[mi], bf[cj], acc[mi][cj], 0, 0, 0);
    }
    unsigned short* kxd = KXpb + (size_t)ch * BB * DD * CC + (size_t)b * DD * CC;
#pragma unroll
    for (int mi = 0; mi < 4; ++mi)
#pragma unroll
        for (int cj = 0; cj < 4; ++cj)
#pragma unroll
            for (int r = 0; r < 4; ++r) {
                int m = mi * 16 + 4 * g + r;
                int c = cw + cj * 16 + l16;
                kxd[(size_t)m * CC + c] = (unsigned short)bf16s(acc[mi][cj][r]);
            }
}

// ---- KVTb[b][c][m] = sum_cp KX[b][m][cp]*Wv[c][cp] + bv[c]*Ksum[b][m]
//      FUSED reduction: B-fragment = fp32 sum of the 8 KXpb chunk partials,
//      rounded once to bf16 (bit-identical to the old red->kv path).
//      Single-bf16 MFMA. ----
__global__ __launch_bounds__(256) void k_kv(const unsigned short* __restrict__ KXpb,
                                            const float* __restrict__ Wv,
                                            const float* __restrict__ bv,
                                            const float* __restrict__ Ksum,
                                            __hip_bfloat16* __restrict__ KVTb) {
    int b = blockIdx.y;
    int c0 = blockIdx.x * 64;
    int wave = threadIdx.x >> 6, lane = threadIdx.x & 63;
    int cw = c0 + wave * 16;                  // wave owns 16 c-rows, all 64 m
    int l16 = lane & 15, g = lane >> 4;

    const size_t chstride = (size_t)BB * DD * CC;   // shorts per chunk
    f32x4 acc[4] = {};                        // [mj]
    const float* wvp = Wv + (size_t)(cw + l16) * CC;
    const unsigned short* kxp = KXpb + (size_t)b * DD * CC;

#pragma unroll
    for (int ck = 0; ck < 16; ++ck) {         // 512 cp in steps of 32
        int cp = ck * 32 + g * 8;
        f32x4 w0 = *reinterpret_cast<const f32x4*>(wvp + cp);
        f32x4 w1 = *reinterpret_cast<const f32x4*>(wvp + cp + 4);
        short8 a;
#pragma unroll
        for (int e = 0; e < 4; ++e) { a[e] = bf16s(w0[e]); a[4 + e] = bf16s(w1[e]); }
#pragma unroll
        for (int mj = 0; mj < 4; ++mj) {
            const unsigned short* base = kxp + (size_t)(mj * 16 + l16) * CC + cp;
            float s[8] = {};
#pragma unroll
            for (int chn = 0; chn < NCH; ++chn) {
                short8 v = *reinterpret_cast<const short8*>(base + chn * chstride);
#pragma unroll
                for (int e = 0; e < 8; ++e) s[e] += sbf16(v[e]);
            }
            short8 bfr;
#pragma unroll
            for (int e = 0; e < 8; ++e) bfr[e] = bf16s(s[e]);
            acc[mj] = __builtin_amdgcn_mfma_f32_16x16x32_bf16(a, bfr, acc[mj], 0, 0, 0);
        }
    }
#pragma unroll
    for (int mj = 0; mj < 4; ++mj)
#pragma unroll
        for (int r = 0; r < 4; ++r) {
            int c = cw + 4 * g + r;
            int m = mj * 16 + l16;
            KVTb[((size_t)b * CC + c) * DD + m] =
                __float2bfloat16(acc[mj][r] + bv[c] * Ksum[b * DD + m]);
        }
}

// ---- out[c][n] = xb16 + (gamma/dot(Q[n],Ksum+eps)) * sum_m KVT[c][m]*Q[n][m]
//      MFMA K=64, norm fused, nontemporal x-load + out-store.
//      1D grid 2048 with chunked XCD swizzle. ----
__global__ __launch_bounds__(256) void k_out(const __hip_bfloat16* __restrict__ xb16,
                                             const __hip_bfloat16* __restrict__ Qb,
                                             const __hip_bfloat16* __restrict__ KVTb,
                                             const float* __restrict__ Ksum,
                                             const float* __restrict__ gamma,
                                             float* __restrict__ out) {
    // chunked XCD swizzle (bijective: 2048 = 8 * 256)
    int d = blockIdx.x;
    int logical = (d & 7) * 256 + (d >> 3);
    int c_blk = (logical & 3) * 128;
    int n_blk = ((logical >> 2) & 31) * 128;
    int b = logical >> 7;

    int wave = threadIdx.x >> 6, lane = threadIdx.x & 63;
    int cw = c_blk + (wave >> 1) * 64, nw = n_blk + (wave & 1) * 64;
    int l16 = lane & 15, g = lane >> 4;

    float ksv[2][8];
#pragma unroll
    for (int ck = 0; ck < 2; ++ck)
#pragma unroll
        for (int e = 0; e < 8; ++e)
            ksv[ck][e] = Ksum[b * DD + (ck * 4 + g) * 8 + e] + EPSV;

    f32x4 acc[4][4] = {};
    float dot[4] = {0.f, 0.f, 0.f, 0.f};
    const short8* ap = reinterpret_cast<const short8*>(KVTb) + ((size_t)b * CC + cw) * 8;
    const short8* bp = reinterpret_cast<const short8*>(Qb) + ((size_t)b * NN + nw) * 8;
#pragma unroll
    for (int ck = 0; ck < 2; ++ck) {
        int ch = ck * 4 + g;
        short8 af[4], bf[4];
#pragma unroll
        for (int i = 0; i < 4; ++i) af[i] = ap[(size_t)(i * 16 + l16) * 8 + ch];
#pragma unroll
        for (int i = 0; i < 4; ++i) bf[i] = bp[(size_t)(i * 16 + l16) * 8 + ch];
#pragma unroll
        for (int j = 0; j < 4; ++j)
#pragma unroll
            for (int e = 0; e < 8; ++e)
                dot[j] = fmaf(sbf16(bf[j][e]), ksv[ck][e], dot[j]);
#pragma unroll
        for (int i = 0; i < 4; ++i)
#pragma unroll
            for (int j = 0; j < 4; ++j)
                acc[i][j] = __builtin_amdgcn_mfma_f32_16x16x32_bf16(af[i], bf[j], acc[i][j], 0, 0, 0);
    }
    float gm = gamma[0];
    float sc[4];
#pragma unroll
    for (int j = 0; j < 4; ++j) {
        float d2 = dot[j];
        d2 += __shfl_xor(d2, 16, 64);
        d2 += __shfl_xor(d2, 32, 64);
        sc[j] = gm / d2;
    }
    const unsigned short* xb = reinterpret_cast<const unsigned short*>(xb16)
                               + (size_t)b * CC * NN;
    float* ob = out + (size_t)b * CC * NN;
#pragma unroll
    for (int i = 0; i < 4; ++i)
#pragma unroll
        for (int r = 0; r < 4; ++r) {
            int c = cw + i * 16 + 4 * g + r;
            size_t rowoff = (size_t)c * NN;
#pragma unroll
            for (int j = 0; j < 4; ++j) {
                int n = nw + j * 16 + l16;
                unsigned short xraw = __builtin_nontemporal_load(&xb[rowoff + n]);
                float xv = sbf16((short)xraw);
                __builtin_nontemporal_store(xv + sc[j] * acc[i][j][r], &ob[rowoff + n]);
            }
        }
}

extern "C" void kernel_launch(void* const* d_in, const int* in_sizes, int n_in,
                              void* d_out, int out_size, void* d_ws, size_t ws_size,
                              hipStream_t stream) {
    const float* x     = (const float*)d_in[0];
    const float* Wq    = (const float*)d_in[1];
    const float* bq    = (const float*)d_in[2];
    const float* Wk    = (const float*)d_in[3];
    const float* bk    = (const float*)d_in[4];
    const float* Wv    = (const float*)d_in[5];
    const float* bv    = (const float*)d_in[6];
    const float* gamma = (const float*)d_in[7];
    float* out = (float*)d_out;

    float* ws    = (float*)d_ws;
    unsigned short* KXpb = (unsigned short*)ws;                 // NCH*B*D*C bf16 (8MB)
    float* Ksum  = (float*)(KXpb + (size_t)NCH * BB * DD * CC); // B*D fp32
    __hip_bfloat16* Qb   = (__hip_bfloat16*)(Ksum + BB * DD);   // B*N*D bf16
    __hip_bfloat16* Kb   = Qb + (size_t)BB * NN * DD;           // B*D*N bf16
    __hip_bfloat16* KVTb = Kb + (size_t)BB * DD * NN;           // B*C*D bf16
    __hip_bfloat16* Wcat = KVTb + (size_t)BB * CC * DD;         // 128*C bf16
    __hip_bfloat16* xb16 = Wcat + 128 * CC;                     // B*C*N bf16 (67MB)

    k_prep<<<dim3(257), dim3(256), 0, stream>>>(Wq, Wk, Wcat, Ksum);
    k_proj<<<dim3(NN / 128, BB), dim3(256), 0, stream>>>(x, Wcat, bq, bk, Qb, Kb, xb16, Ksum);
    k_kx<<<dim3(2, NCH, BB), dim3(256), 0, stream>>>(Kb, xb16, KXpb);
    k_kv<<<dim3(CC / 64, BB), dim3(256), 0, stream>>>(KXpb, Wv, bv, Ksum, KVTb);
    k_out<<<dim3(2048), dim3(256), 0, stream>>>(xb16, Qb, KVTb, Ksum, gamma, out);
}

// Round 24
// 184.588 us; speedup vs baseline: 1.2743x; 1.2743x over previous
//
#include <hip/hip_runtime.h>
#include <hip/hip_bf16.h>
#include <math.h>

#define BB 16
#define CC 512
#define DD 64
#define NN 4096
#define EPSV 1e-6f
#define NCH 8   // split-K chunks for KX

typedef __attribute__((ext_vector_type(8))) short short8;
typedef __attribute__((ext_vector_type(4))) short s16x4;
typedef __attribute__((ext_vector_type(4))) float f32x4;

// fast softplus: hardware v_exp_f32 / v_log_f32 (arg of log in (1,2])
__device__ __forceinline__ float softplus_f(float v) {
    return fmaxf(v, 0.0f) + __logf(1.0f + __expf(-fabsf(v)));
}
__device__ __forceinline__ short bf16s(float f) {
    __hip_bfloat16 h = __float2bfloat16(f);
    return __builtin_bit_cast(short, h);
}
__device__ __forceinline__ float sbf16(short s) {
    return __bfloat162float(__builtin_bit_cast(__hip_bfloat16, s));
}

// ---- prep: Wcat bf16 [128][512] (blocks 0-255), zero Ksum (block 256) ----
__global__ __launch_bounds__(256) void k_prep(const float* __restrict__ Wq,
                                              const float* __restrict__ Wk,
                                              __hip_bfloat16* __restrict__ Wcat,
                                              float* __restrict__ Ksum) {
    int blk = blockIdx.x;
    if (blk < 256) {
        int i = blk * 256 + threadIdx.x;
        int j = i >> 9, c = i & 511;
        float v = (j < DD) ? Wq[j * CC + c] : Wk[(j - DD) * CC + c];
        Wcat[i] = __float2bfloat16(v);
    } else {
        f32x4 z = {0.f, 0.f, 0.f, 0.f};
        reinterpret_cast<f32x4*>(Ksum)[threadIdx.x] = z;  // 1024 floats
    }
}

// ---- Q/K projection via MFMA (measured-best r6 path, relaxed barrier).
//      Also emits xb16[b][c][n] (bf16 copy of x). Fused Ksum.
//      Qb[b][n][d] bf16 ; Kb[b][m][n] bf16 ----
__global__ __launch_bounds__(256) void k_proj(const float* __restrict__ x,
                                              const __hip_bfloat16* __restrict__ Wcat,
                                              const float* __restrict__ bq,
                                              const float* __restrict__ bk,
                                              __hip_bfloat16* __restrict__ Qb,
                                              __hip_bfloat16* __restrict__ Kb,
                                              __hip_bfloat16* __restrict__ xb16,
                                              float* __restrict__ Ksum) {
    __shared__ unsigned short xs[2][32][132];
    __shared__ unsigned short ws[2][128][40];

    int b = blockIdx.y;
    int n_blk = blockIdx.x * 128;
    int t = threadIdx.x;
    int wave = t >> 6, lane = t & 63;
    int nwl = wave * 32;                    // wave's local n base
    int n_wave = n_blk + nwl;
    int l16 = lane & 15, g = lane >> 4;

    int sv = t & 31;
    int sc = t >> 5;
    int wj = t >> 1;
    int wh = t & 1;

    const float* xb = x + (size_t)b * CC * NN + n_blk + sv * 4;
    unsigned short* xg = reinterpret_cast<unsigned short*>(xb16)
                         + (size_t)b * CC * NN + n_blk + sv * 4;
    const unsigned short* wg = reinterpret_cast<const unsigned short*>(Wcat)
                               + (size_t)wj * 512 + wh * 16;

    f32x4 xr[4];
    s16x4 wr[4];

    auto loadx = [&](int c0) {
#pragma unroll
        for (int i = 0; i < 4; ++i)
            xr[i] = *reinterpret_cast<const f32x4*>(xb + (size_t)(c0 + sc + i * 8) * NN);
    };
    auto loadw = [&](int c0) {
#pragma unroll
        for (int k = 0; k < 4; ++k)
            wr[k] = *reinterpret_cast<const s16x4*>(wg + c0 + k * 4);
    };
    auto writex = [&](int bi, int c0) {
#pragma unroll
        for (int i = 0; i < 4; ++i) {
            s16x4 pv;
#pragma unroll
            for (int j = 0; j < 4; ++j) pv[j] = bf16s(xr[i][j]);
            *reinterpret_cast<s16x4*>(&xs[bi][sc + i * 8][sv * 4]) = pv;
            *reinterpret_cast<s16x4*>(&xg[(size_t)(c0 + sc + i * 8) * NN]) = pv;
        }
    };
    auto writew = [&](int bi) {
#pragma unroll
        for (int k = 0; k < 4; ++k)
            *reinterpret_cast<s16x4*>(&ws[bi][wj][wh * 16 + k * 4]) = wr[k];
    };

    f32x4 accQ[2][4] = {};
    f32x4 accK[4][2] = {};

    loadx(0); loadw(0);
    writex(0, 0); writew(0);

    for (int ck = 0; ck < 16; ++ck) {
        int cur = ck & 1;
        if (ck < 15) { loadx((ck + 1) * 32); loadw((ck + 1) * 32); }
        asm volatile("s_waitcnt lgkmcnt(0)" ::: "memory");
        __builtin_amdgcn_s_barrier();
        short8 xf[2], wf[8];
#pragma unroll
        for (int nf = 0; nf < 2; ++nf) {
            short8 v;
#pragma unroll
            for (int e = 0; e < 8; ++e)
                v[e] = (short)xs[cur][g * 8 + e][nwl + nf * 16 + l16];
            xf[nf] = v;
        }
#pragma unroll
        for (int jf = 0; jf < 8; ++jf)
            wf[jf] = *reinterpret_cast<const short8*>(&ws[cur][jf * 16 + l16][g * 8]);
#pragma unroll
        for (int nf = 0; nf < 2; ++nf)
#pragma unroll
            for (int jf = 0; jf < 4; ++jf)
                accQ[nf][jf] = __builtin_amdgcn_mfma_f32_16x16x32_bf16(xf[nf], wf[jf], accQ[nf][jf], 0, 0, 0);
#pragma unroll
        for (int jf = 0; jf < 4; ++jf)
#pragma unroll
            for (int nf = 0; nf < 2; ++nf)
                accK[jf][nf] = __builtin_amdgcn_mfma_f32_16x16x32_bf16(wf[4 + jf], xf[nf], accK[jf][nf], 0, 0, 0);
        if (ck < 15) { writex(cur ^ 1, (ck + 1) * 32); writew(cur ^ 1); }
    }

#pragma unroll
    for (int nf = 0; nf < 2; ++nf)
#pragma unroll
        for (int jf = 0; jf < 4; ++jf)
#pragma unroll
            for (int r = 0; r < 4; ++r) {
                int n = n_wave + nf * 16 + 4 * g + r;
                int j = jf * 16 + l16;
                float v = softplus_f(accQ[nf][jf][r] + bq[j]);
                Qb[((size_t)b * NN + n) * DD + j] = __float2bfloat16(v);
            }
#pragma unroll
    for (int jf = 0; jf < 4; ++jf)
#pragma unroll
        for (int r = 0; r < 4; ++r) {
            int m = jf * 16 + 4 * g + r;
            float s = 0.f;
#pragma unroll
            for (int nf = 0; nf < 2; ++nf) {
                int n = n_wave + nf * 16 + l16;
                float v = softplus_f(accK[jf][nf][r] + bk[m]);
                Kb[((size_t)b * DD + m) * NN + n] = __float2bfloat16(v);
                s += v;
            }
            s += __shfl_xor(s, 1, 64);
            s += __shfl_xor(s, 2, 64);
            s += __shfl_xor(s, 4, 64);
            s += __shfl_xor(s, 8, 64);
            if (l16 == 0) atomicAdd(&Ksum[b * DD + m], s);
        }
}

// ---- KXpb[ch][b][m][c] (bf16) = sum_{nn in chunk} Kb[m][nn]*xb16[c][nn]
//      (MFMA, no LDS, no atomics, bf16 partials) ----
__global__ __launch_bounds__(256) void k_kx(const __hip_bfloat16* __restrict__ Kb,
                                            const __hip_bfloat16* __restrict__ xb16,
                                            unsigned short* __restrict__ KXpb) {
    int b = blockIdx.z;
    int ch = blockIdx.y;                      // 8 n-chunks of 512
    int n0 = ch * 512;
    int c0 = blockIdx.x * 256;                // 2 c-halves
    int wave = threadIdx.x >> 6, lane = threadIdx.x & 63;
    int cw = c0 + wave * 64;                  // wave owns 64 c-cols
    int l16 = lane & 15, g = lane >> 4;

    f32x4 acc[4][4] = {};                     // [mi][cj]
    const __hip_bfloat16* kp = Kb + (size_t)b * DD * NN;
    const __hip_bfloat16* xp = xb16 + (size_t)b * CC * NN;

#pragma unroll 4
    for (int ks = 0; ks < 16; ++ks) {         // 512 n in steps of 32
        int nk = n0 + ks * 32 + g * 8;
        short8 af[4], bf[4];
#pragma unroll
        for (int mi = 0; mi < 4; ++mi)
            af[mi] = *reinterpret_cast<const short8*>(kp + (size_t)(mi * 16 + l16) * NN + nk);
#pragma unroll
        for (int cj = 0; cj < 4; ++cj)
            bf[cj] = *reinterpret_cast<const short8*>(xp + (size_t)(cw + cj * 16 + l16) * NN + nk);
#pragma unroll
        for (int mi = 0; mi < 4; ++mi)
#pragma unroll
            for (int cj = 0; cj < 4; ++cj)
                acc[mi][cj] = __builtin_amdgcn_mfma_f32_16x16x32_bf16(af[mi], bf[cj], acc[mi][cj], 0, 0, 0);
    }
    unsigned short* kxd = KXpb + (size_t)ch * BB * DD * CC + (size_t)b * DD * CC;
#pragma unroll
    for (int mi = 0; mi < 4; ++mi)
#pragma unroll
        for (int cj = 0; cj < 4; ++cj)
#pragma unroll
            for (int r = 0; r < 4; ++r) {
                int m = mi * 16 + 4 * g + r;
                int c = cw + cj * 16 + l16;
                kxd[(size_t)m * CC + c] = (unsigned short)bf16s(acc[mi][cj][r]);
            }
}

// ---- KVTb[b][c][m] = sum_cp KX[b][m][cp]*Wv[c][cp] + bv[c]*Ksum[b][m]
//      FUSED reduction: B-fragment = fp32 sum of the 8 KXpb chunk partials,
//      rounded once to bf16. Single-bf16 MFMA. ----
__global__ __launch_bounds__(256) void k_kv(const unsigned short* __restrict__ KXpb,
                                            const float* __restrict__ Wv,
                                            const float* __restrict__ bv,
                                            const float* __restrict__ Ksum,
                                            __hip_bfloat16* __restrict__ KVTb) {
    int b = blockIdx.y;
    int c0 = blockIdx.x * 64;
    int wave = threadIdx.x >> 6, lane = threadIdx.x & 63;
    int cw = c0 + wave * 16;                  // wave owns 16 c-rows, all 64 m
    int l16 = lane & 15, g = lane >> 4;

    const size_t chstride = (size_t)BB * DD * CC;   // shorts per chunk
    f32x4 acc[4] = {};                        // [mj]
    const float* wvp = Wv + (size_t)(cw + l16) * CC;
    const unsigned short* kxp = KXpb + (size_t)b * DD * CC;

#pragma unroll
    for (int ck = 0; ck < 16; ++ck) {         // 512 cp in steps of 32
        int cp = ck * 32 + g * 8;
        f32x4 w0 = *reinterpret_cast<const f32x4*>(wvp + cp);
        f32x4 w1 = *reinterpret_cast<const f32x4*>(wvp + cp + 4);
        short8 a;
#pragma unroll
        for (int e = 0; e < 4; ++e) { a[e] = bf16s(w0[e]); a[4 + e] = bf16s(w1[e]); }
#pragma unroll
        for (int mj = 0; mj < 4; ++mj) {
            const unsigned short* base = kxp + (size_t)(mj * 16 + l16) * CC + cp;
            float s[8] = {};
#pragma unroll
            for (int chn = 0; chn < NCH; ++chn) {
                short8 v = *reinterpret_cast<const short8*>(base + chn * chstride);
#pragma unroll
                for (int e = 0; e < 8; ++e) s[e] += sbf16(v[e]);
            }
            short8 bfr;
#pragma unroll
            for (int e = 0; e < 8; ++e) bfr[e] = bf16s(s[e]);
            acc[mj] = __builtin_amdgcn_mfma_f32_16x16x32_bf16(a, bfr, acc[mj], 0, 0, 0);
        }
    }
#pragma unroll
    for (int mj = 0; mj < 4; ++mj)
#pragma unroll
        for (int r = 0; r < 4; ++r) {
            int c = cw + 4 * g + r;
            int m = mj * 16 + l16;
            KVTb[((size_t)b * CC + c) * DD + m] =
                __float2bfloat16(acc[mj][r] + bv[c] * Ksum[b * DD + m]);
        }
}

// ---- out[c][n] = xb16 + (gamma/dot(Q[n],Ksum+eps)) * sum_m KVT[c][m]*Q[n][m]
//      MFMA K=64, norm fused, CACHED x-load (NT load was the r23 regression),
//      nontemporal out-stores. 1D grid 2048 with chunked XCD swizzle. ----
__global__ __launch_bounds__(256) void k_out(const __hip_bfloat16* __restrict__ xb16,
                                             const __hip_bfloat16* __restrict__ Qb,
                                             const __hip_bfloat16* __restrict__ KVTb,
                                             const float* __restrict__ Ksum,
                                             const float* __restrict__ gamma,
                                             float* __restrict__ out) {
    // chunked XCD swizzle (bijective: 2048 = 8 * 256)
    int d = blockIdx.x;
    int logical = (d & 7) * 256 + (d >> 3);
    int c_blk = (logical & 3) * 128;
    int n_blk = ((logical >> 2) & 31) * 128;
    int b = logical >> 7;

    int wave = threadIdx.x >> 6, lane = threadIdx.x & 63;
    int cw = c_blk + (wave >> 1) * 64, nw = n_blk + (wave & 1) * 64;
    int l16 = lane & 15, g = lane >> 4;

    float ksv[2][8];
#pragma unroll
    for (int ck = 0; ck < 2; ++ck)
#pragma unroll
        for (int e = 0; e < 8; ++e)
            ksv[ck][e] = Ksum[b * DD + (ck * 4 + g) * 8 + e] + EPSV;

    f32x4 acc[4][4] = {};
    float dot[4] = {0.f, 0.f, 0.f, 0.f};
    const short8* ap = reinterpret_cast<const short8*>(KVTb) + ((size_t)b * CC + cw) * 8;
    const short8* bp = reinterpret_cast<const short8*>(Qb) + ((size_t)b * NN + nw) * 8;
#pragma unroll
    for (int ck = 0; ck < 2; ++ck) {
        int ch = ck * 4 + g;
        short8 af[4], bf[4];
#pragma unroll
        for (int i = 0; i < 4; ++i) af[i] = ap[(size_t)(i * 16 + l16) * 8 + ch];
#pragma unroll
        for (int i = 0; i < 4; ++i) bf[i] = bp[(size_t)(i * 16 + l16) * 8 + ch];
#pragma unroll
        for (int j = 0; j < 4; ++j)
#pragma unroll
            for (int e = 0; e < 8; ++e)
                dot[j] = fmaf(sbf16(bf[j][e]), ksv[ck][e], dot[j]);
#pragma unroll
        for (int i = 0; i < 4; ++i)
#pragma unroll
            for (int j = 0; j < 4; ++j)
                acc[i][j] = __builtin_amdgcn_mfma_f32_16x16x32_bf16(af[i], bf[j], acc[i][j], 0, 0, 0);
    }
    float gm = gamma[0];
    float sc[4];
#pragma unroll
    for (int j = 0; j < 4; ++j) {
        float d2 = dot[j];
        d2 += __shfl_xor(d2, 16, 64);
        d2 += __shfl_xor(d2, 32, 64);
        sc[j] = gm / d2;
    }
    const __hip_bfloat16* xb = xb16 + (size_t)b * CC * NN;
    float* ob = out + (size_t)b * CC * NN;
#pragma unroll
    for (int i = 0; i < 4; ++i)
#pragma unroll
        for (int r = 0; r < 4; ++r) {
            int c = cw + i * 16 + 4 * g + r;
            size_t rowoff = (size_t)c * NN;
#pragma unroll
            for (int j = 0; j < 4; ++j) {
                int n = nw + j * 16 + l16;
                float xv = __bfloat162float(xb[rowoff + n]);
                __builtin_nontemporal_store(xv + sc[j] * acc[i][j][r], &ob[rowoff + n]);
            }
        }
}

extern "C" void kernel_launch(void* const* d_in, const int* in_sizes, int n_in,
                              void* d_out, int out_size, void* d_ws, size_t ws_size,
                              hipStream_t stream) {
    const float* x     = (const float*)d_in[0];
    const float* Wq    = (const float*)d_in[1];
    const float* bq    = (const float*)d_in[2];
    const float* Wk    = (const float*)d_in[3];
    const float* bk    = (const float*)d_in[4];
    const float* Wv    = (const float*)d_in[5];
    const float* bv    = (const float*)d_in[6];
    const float* gamma = (const float*)d_in[7];
    float* out = (float*)d_out;

    float* ws    = (float*)d_ws;
    unsigned short* KXpb = (unsigned short*)ws;                 // NCH*B*D*C bf16 (8MB)
    float* Ksum  = (float*)(KXpb + (size_t)NCH * BB * DD * CC); // B*D fp32
    __hip_bfloat16* Qb   = (__hip_bfloat16*)(Ksum + BB * DD);   // B*N*D bf16
    __hip_bfloat16* Kb   = Qb + (size_t)BB * NN * DD;           // B*D*N bf16
    __hip_bfloat16* KVTb = Kb + (size_t)BB * DD * NN;           // B*C*D bf16
    __hip_bfloat16* Wcat = KVTb + (size_t)BB * CC * DD;         // 128*C bf16
    __hip_bfloat16* xb16 = Wcat + 128 * CC;                     // B*C*N bf16 (67MB)

    k_prep<<<dim3(257), dim3(256), 0, stream>>>(Wq, Wk, Wcat, Ksum);
    k_proj<<<dim3(NN / 128, BB), dim3(256), 0, stream>>>(x, Wcat, bq, bk, Qb, Kb, xb16, Ksum);
    k_kx<<<dim3(2, NCH, BB), dim3(256), 0, stream>>>(Kb, xb16, KXpb);
    k_kv<<<dim3(CC / 64, BB), dim3(256), 0, stream>>>(KXpb, Wv, bv, Ksum, KVTb);
    k_out<<<dim3(2048), dim3(256), 0, stream>>>(xb16, Qb, KVTb, Ksum, gamma, out);
}

// Round 25
// 146.527 us; speedup vs baseline: 1.6053x; 1.2598x over previous
//
#include <hip/hip_runtime.h>
#include <hip/hip_bf16.h>
#include <math.h>

#define BB 16
#define CC 512
#define DD 64
#define NN 4096
#define EPSV 1e-6f
#define NCH 8   // split-K chunks for KX

typedef __attribute__((ext_vector_type(8))) short short8;
typedef __attribute__((ext_vector_type(4))) short s16x4;
typedef __attribute__((ext_vector_type(4))) float f32x4;

// fast softplus: hardware v_exp_f32 / v_log_f32 (arg of log in (1,2])
__device__ __forceinline__ float softplus_f(float v) {
    return fmaxf(v, 0.0f) + __logf(1.0f + __expf(-fabsf(v)));
}
__device__ __forceinline__ short bf16s(float f) {
    __hip_bfloat16 h = __float2bfloat16(f);
    return __builtin_bit_cast(short, h);
}
__device__ __forceinline__ float sbf16(short s) {
    return __bfloat162float(__builtin_bit_cast(__hip_bfloat16, s));
}

// ---- prep: Wcat bf16 [128][512] (blocks 0-255), zero Ksum (block 256) ----
__global__ __launch_bounds__(256) void k_prep(const float* __restrict__ Wq,
                                              const float* __restrict__ Wk,
                                              __hip_bfloat16* __restrict__ Wcat,
                                              float* __restrict__ Ksum) {
    int blk = blockIdx.x;
    if (blk < 256) {
        int i = blk * 256 + threadIdx.x;
        int j = i >> 9, c = i & 511;
        float v = (j < DD) ? Wq[j * CC + c] : Wk[(j - DD) * CC + c];
        Wcat[i] = __float2bfloat16(v);
    } else {
        f32x4 z = {0.f, 0.f, 0.f, 0.f};
        reinterpret_cast<f32x4*>(Ksum)[threadIdx.x] = z;  // 1024 floats
    }
}

// ---- Q/K projection via MFMA (measured-best r6 path, relaxed barrier).
//      Also emits xb16[b][c][n] (bf16 copy of x). Fused Ksum.
//      Qb[b][n][d] bf16 ; Kb[b][m][n] bf16 ----
__global__ __launch_bounds__(256) void k_proj(const float* __restrict__ x,
                                              const __hip_bfloat16* __restrict__ Wcat,
                                              const float* __restrict__ bq,
                                              const float* __restrict__ bk,
                                              __hip_bfloat16* __restrict__ Qb,
                                              __hip_bfloat16* __restrict__ Kb,
                                              __hip_bfloat16* __restrict__ xb16,
                                              float* __restrict__ Ksum) {
    __shared__ unsigned short xs[2][32][132];
    __shared__ unsigned short ws[2][128][40];

    int b = blockIdx.y;
    int n_blk = blockIdx.x * 128;
    int t = threadIdx.x;
    int wave = t >> 6, lane = t & 63;
    int nwl = wave * 32;                    // wave's local n base
    int n_wave = n_blk + nwl;
    int l16 = lane & 15, g = lane >> 4;

    int sv = t & 31;
    int sc = t >> 5;
    int wj = t >> 1;
    int wh = t & 1;

    const float* xb = x + (size_t)b * CC * NN + n_blk + sv * 4;
    unsigned short* xg = reinterpret_cast<unsigned short*>(xb16)
                         + (size_t)b * CC * NN + n_blk + sv * 4;
    const unsigned short* wg = reinterpret_cast<const unsigned short*>(Wcat)
                               + (size_t)wj * 512 + wh * 16;

    f32x4 xr[4];
    s16x4 wr[4];

    auto loadx = [&](int c0) {
#pragma unroll
        for (int i = 0; i < 4; ++i)
            xr[i] = *reinterpret_cast<const f32x4*>(xb + (size_t)(c0 + sc + i * 8) * NN);
    };
    auto loadw = [&](int c0) {
#pragma unroll
        for (int k = 0; k < 4; ++k)
            wr[k] = *reinterpret_cast<const s16x4*>(wg + c0 + k * 4);
    };
    auto writex = [&](int bi, int c0) {
#pragma unroll
        for (int i = 0; i < 4; ++i) {
            s16x4 pv;
#pragma unroll
            for (int j = 0; j < 4; ++j) pv[j] = bf16s(xr[i][j]);
            *reinterpret_cast<s16x4*>(&xs[bi][sc + i * 8][sv * 4]) = pv;
            *reinterpret_cast<s16x4*>(&xg[(size_t)(c0 + sc + i * 8) * NN]) = pv;
        }
    };
    auto writew = [&](int bi) {
#pragma unroll
        for (int k = 0; k < 4; ++k)
            *reinterpret_cast<s16x4*>(&ws[bi][wj][wh * 16 + k * 4]) = wr[k];
    };

    f32x4 accQ[2][4] = {};
    f32x4 accK[4][2] = {};

    loadx(0); loadw(0);
    writex(0, 0); writew(0);

    for (int ck = 0; ck < 16; ++ck) {
        int cur = ck & 1;
        if (ck < 15) { loadx((ck + 1) * 32); loadw((ck + 1) * 32); }
        asm volatile("s_waitcnt lgkmcnt(0)" ::: "memory");
        __builtin_amdgcn_s_barrier();
        short8 xf[2], wf[8];
#pragma unroll
        for (int nf = 0; nf < 2; ++nf) {
            short8 v;
#pragma unroll
            for (int e = 0; e < 8; ++e)
                v[e] = (short)xs[cur][g * 8 + e][nwl + nf * 16 + l16];
            xf[nf] = v;
        }
#pragma unroll
        for (int jf = 0; jf < 8; ++jf)
            wf[jf] = *reinterpret_cast<const short8*>(&ws[cur][jf * 16 + l16][g * 8]);
#pragma unroll
        for (int nf = 0; nf < 2; ++nf)
#pragma unroll
            for (int jf = 0; jf < 4; ++jf)
                accQ[nf][jf] = __builtin_amdgcn_mfma_f32_16x16x32_bf16(xf[nf], wf[jf], accQ[nf][jf], 0, 0, 0);
#pragma unroll
        for (int jf = 0; jf < 4; ++jf)
#pragma unroll
            for (int nf = 0; nf < 2; ++nf)
                accK[jf][nf] = __builtin_amdgcn_mfma_f32_16x16x32_bf16(wf[4 + jf], xf[nf], accK[jf][nf], 0, 0, 0);
        if (ck < 15) { writex(cur ^ 1, (ck + 1) * 32); writew(cur ^ 1); }
    }

#pragma unroll
    for (int nf = 0; nf < 2; ++nf)
#pragma unroll
        for (int jf = 0; jf < 4; ++jf)
#pragma unroll
            for (int r = 0; r < 4; ++r) {
                int n = n_wave + nf * 16 + 4 * g + r;
                int j = jf * 16 + l16;
                float v = softplus_f(accQ[nf][jf][r] + bq[j]);
                Qb[((size_t)b * NN + n) * DD + j] = __float2bfloat16(v);
            }
#pragma unroll
    for (int jf = 0; jf < 4; ++jf)
#pragma unroll
        for (int r = 0; r < 4; ++r) {
            int m = jf * 16 + 4 * g + r;
            float s = 0.f;
#pragma unroll
            for (int nf = 0; nf < 2; ++nf) {
                int n = n_wave + nf * 16 + l16;
                float v = softplus_f(accK[jf][nf][r] + bk[m]);
                Kb[((size_t)b * DD + m) * NN + n] = __float2bfloat16(v);
                s += v;
            }
            s += __shfl_xor(s, 1, 64);
            s += __shfl_xor(s, 2, 64);
            s += __shfl_xor(s, 4, 64);
            s += __shfl_xor(s, 8, 64);
            if (l16 == 0) atomicAdd(&Ksum[b * DD + m], s);
        }
}

// ---- KXpb[ch][b][m][c] (bf16) = sum_{nn in chunk} Kb[m][nn]*xb16[c][nn]
//      (MFMA, no LDS, no atomics, bf16 partials) ----
__global__ __launch_bounds__(256) void k_kx(const __hip_bfloat16* __restrict__ Kb,
                                            const __hip_bfloat16* __restrict__ xb16,
                                            unsigned short* __restrict__ KXpb) {
    int b = blockIdx.z;
    int ch = blockIdx.y;                      // 8 n-chunks of 512
    int n0 = ch * 512;
    int c0 = blockIdx.x * 256;                // 2 c-halves
    int wave = threadIdx.x >> 6, lane = threadIdx.x & 63;
    int cw = c0 + wave * 64;                  // wave owns 64 c-cols
    int l16 = lane & 15, g = lane >> 4;

    f32x4 acc[4][4] = {};                     // [mi][cj]
    const __hip_bfloat16* kp = Kb + (size_t)b * DD * NN;
    const __hip_bfloat16* xp = xb16 + (size_t)b * CC * NN;

#pragma unroll 4
    for (int ks = 0; ks < 16; ++ks) {         // 512 n in steps of 32
        int nk = n0 + ks * 32 + g * 8;
        short8 af[4], bf[4];
#pragma unroll
        for (int mi = 0; mi < 4; ++mi)
            af[mi] = *reinterpret_cast<const short8*>(kp + (size_t)(mi * 16 + l16) * NN + nk);
#pragma unroll
        for (int cj = 0; cj < 4; ++cj)
            bf[cj] = *reinterpret_cast<const short8*>(xp + (size_t)(cw + cj * 16 + l16) * NN + nk);
#pragma unroll
        for (int mi = 0; mi < 4; ++mi)
#pragma unroll
            for (int cj = 0; cj < 4; ++cj)
                acc[mi][cj] = __builtin_amdgcn_mfma_f32_16x16x32_bf16(af[mi], bf[cj], acc[mi][cj], 0, 0, 0);
    }
    unsigned short* kxd = KXpb + (size_t)ch * BB * DD * CC + (size_t)b * DD * CC;
#pragma unroll
    for (int mi = 0; mi < 4; ++mi)
#pragma unroll
        for (int cj = 0; cj < 4; ++cj)
#pragma unroll
            for (int r = 0; r < 4; ++r) {
                int m = mi * 16 + 4 * g + r;
                int c = cw + cj * 16 + l16;
                kxd[(size_t)m * CC + c] = (unsigned short)bf16s(acc[mi][cj][r]);
            }
}

// ---- KXb = sum over 8 bf16 chunks of KXpb (f32 accumulate, bf16 out) ----
__global__ __launch_bounds__(256) void k_red(const unsigned short* __restrict__ KXpb,
                                             unsigned short* __restrict__ KXb) {
    size_t i = (size_t)blockIdx.x * 256 + threadIdx.x;   // short8 index, 65536 total
    const short8* src = reinterpret_cast<const short8*>(KXpb);
    size_t chstride = (size_t)BB * DD * CC / 8;
    float s[8] = {};
#pragma unroll
    for (int ch = 0; ch < NCH; ++ch) {
        short8 v = src[ch * chstride + i];
#pragma unroll
        for (int e = 0; e < 8; ++e) s[e] += sbf16(v[e]);
    }
    short8 o;
#pragma unroll
    for (int e = 0; e < 8; ++e) o[e] = bf16s(s[e]);
    reinterpret_cast<short8*>(KXb)[i] = o;
}

// ---- KVTb[b][c][m] = sum_cp KXb[b][m][cp]*Wv[c][cp] + bv[c]*Ksum[b][m]
//      single-bf16 MFMA (KX already bf16; KVT output is bf16 anyway) ----
__global__ __launch_bounds__(256) void k_kv(const unsigned short* __restrict__ KXb,
                                            const float* __restrict__ Wv,
                                            const float* __restrict__ bv,
                                            const float* __restrict__ Ksum,
                                            __hip_bfloat16* __restrict__ KVTb) {
    int b = blockIdx.y;
    int c0 = blockIdx.x * 64;
    int wave = threadIdx.x >> 6, lane = threadIdx.x & 63;
    int cw = c0 + wave * 16;                  // wave owns 16 c-rows, all 64 m
    int l16 = lane & 15, g = lane >> 4;

    f32x4 acc[4] = {};                        // [mj]
    const float* wvp = Wv + (size_t)(cw + l16) * CC;
    const unsigned short* kxp = KXb + (size_t)b * DD * CC;

#pragma unroll
    for (int ck = 0; ck < 16; ++ck) {         // 512 cp in steps of 32
        int cp = ck * 32 + g * 8;
        f32x4 w0 = *reinterpret_cast<const f32x4*>(wvp + cp);
        f32x4 w1 = *reinterpret_cast<const f32x4*>(wvp + cp + 4);
        short8 a;
#pragma unroll
        for (int e = 0; e < 4; ++e) { a[e] = bf16s(w0[e]); a[4 + e] = bf16s(w1[e]); }
#pragma unroll
        for (int mj = 0; mj < 4; ++mj) {
            short8 bfr = *reinterpret_cast<const short8*>(kxp + (size_t)(mj * 16 + l16) * CC + cp);
            acc[mj] = __builtin_amdgcn_mfma_f32_16x16x32_bf16(a, bfr, acc[mj], 0, 0, 0);
        }
    }
#pragma unroll
    for (int mj = 0; mj < 4; ++mj)
#pragma unroll
        for (int r = 0; r < 4; ++r) {
            int c = cw + 4 * g + r;
            int m = mj * 16 + l16;
            KVTb[((size_t)b * CC + c) * DD + m] =
                __float2bfloat16(acc[mj][r] + bv[c] * Ksum[b * DD + m]);
        }
}

// ---- out[c][n] = xb16 + (gamma/dot(Q[n],Ksum+eps)) * sum_m KVT[c][m]*Q[n][m]
//      MFMA K=64, norm fused, cached x-load, nontemporal out-stores.
//      1D grid 2048 with chunked XCD swizzle. ----
__global__ __launch_bounds__(256) void k_out(const __hip_bfloat16* __restrict__ xb16,
                                             const __hip_bfloat16* __restrict__ Qb,
                                             const __hip_bfloat16* __restrict__ KVTb,
                                             const float* __restrict__ Ksum,
                                             const float* __restrict__ gamma,
                                             float* __restrict__ out) {
    // chunked XCD swizzle (bijective: 2048 = 8 * 256)
    int d = blockIdx.x;
    int logical = (d & 7) * 256 + (d >> 3);
    int c_blk = (logical & 3) * 128;
    int n_blk = ((logical >> 2) & 31) * 128;
    int b = logical >> 7;

    int wave = threadIdx.x >> 6, lane = threadIdx.x & 63;
    int cw = c_blk + (wave >> 1) * 64, nw = n_blk + (wave & 1) * 64;
    int l16 = lane & 15, g = lane >> 4;

    float ksv[2][8];
#pragma unroll
    for (int ck = 0; ck < 2; ++ck)
#pragma unroll
        for (int e = 0; e < 8; ++e)
            ksv[ck][e] = Ksum[b * DD + (ck * 4 + g) * 8 + e] + EPSV;

    f32x4 acc[4][4] = {};
    float dot[4] = {0.f, 0.f, 0.f, 0.f};
    const short8* ap = reinterpret_cast<const short8*>(KVTb) + ((size_t)b * CC + cw) * 8;
    const short8* bp = reinterpret_cast<const short8*>(Qb) + ((size_t)b * NN + nw) * 8;
#pragma unroll
    for (int ck = 0; ck < 2; ++ck) {
        int ch = ck * 4 + g;
        short8 af[4], bf[4];
#pragma unroll
        for (int i = 0; i < 4; ++i) af[i] = ap[(size_t)(i * 16 + l16) * 8 + ch];
#pragma unroll
        for (int i = 0; i < 4; ++i) bf[i] = bp[(size_t)(i * 16 + l16) * 8 + ch];
#pragma unroll
        for (int j = 0; j < 4; ++j)
#pragma unroll
            for (int e = 0; e < 8; ++e)
                dot[j] = fmaf(sbf16(bf[j][e]), ksv[ck][e], dot[j]);
#pragma unroll
        for (int i = 0; i < 4; ++i)
#pragma unroll
            for (int j = 0; j < 4; ++j)
                acc[i][j] = __builtin_amdgcn_mfma_f32_16x16x32_bf16(af[i], bf[j], acc[i][j], 0, 0, 0);
    }
    float gm = gamma[0];
    float sc[4];
#pragma unroll
    for (int j = 0; j < 4; ++j) {
        float d2 = dot[j];
        d2 += __shfl_xor(d2, 16, 64);
        d2 += __shfl_xor(d2, 32, 64);
        sc[j] = gm / d2;
    }
    const __hip_bfloat16* xb = xb16 + (size_t)b * CC * NN;
    float* ob = out + (size_t)b * CC * NN;
#pragma unroll
    for (int i = 0; i < 4; ++i)
#pragma unroll
        for (int r = 0; r < 4; ++r) {
            int c = cw + i * 16 + 4 * g + r;
            size_t rowoff = (size_t)c * NN;
#pragma unroll
            for (int j = 0; j < 4; ++j) {
                int n = nw + j * 16 + l16;
                float xv = __bfloat162float(xb[rowoff + n]);
                __builtin_nontemporal_store(xv + sc[j] * acc[i][j][r], &ob[rowoff + n]);
            }
        }
}

extern "C" void kernel_launch(void* const* d_in, const int* in_sizes, int n_in,
                              void* d_out, int out_size, void* d_ws, size_t ws_size,
                              hipStream_t stream) {
    const float* x     = (const float*)d_in[0];
    const float* Wq    = (const float*)d_in[1];
    const float* bq    = (const float*)d_in[2];
    const float* Wk    = (const float*)d_in[3];
    const float* bk    = (const float*)d_in[4];
    const float* Wv    = (const float*)d_in[5];
    const float* bv    = (const float*)d_in[6];
    const float* gamma = (const float*)d_in[7];
    float* out = (float*)d_out;

    float* ws    = (float*)d_ws;
    unsigned short* KXb  = (unsigned short*)ws;                 // B*D*C bf16 (1MB)
    unsigned short* KXpb = KXb + (size_t)BB * DD * CC;          // NCH*B*D*C bf16 (8MB)
    float* Ksum  = (float*)(KXpb + (size_t)NCH * BB * DD * CC); // B*D fp32
    __hip_bfloat16* Qb   = (__hip_bfloat16*)(Ksum + BB * DD);   // B*N*D bf16
    __hip_bfloat16* Kb   = Qb + (size_t)BB * NN * DD;           // B*D*N bf16
    __hip_bfloat16* KVTb = Kb + (size_t)BB * DD * NN;           // B*C*D bf16
    __hip_bfloat16* Wcat = KVTb + (size_t)BB * CC * DD;         // 128*C bf16
    __hip_bfloat16* xb16 = Wcat + 128 * CC;                     // B*C*N bf16 (67MB)

    k_prep<<<dim3(257), dim3(256), 0, stream>>>(Wq, Wk, Wcat, Ksum);
    k_proj<<<dim3(NN / 128, BB), dim3(256), 0, stream>>>(x, Wcat, bq, bk, Qb, Kb, xb16, Ksum);
    k_kx<<<dim3(2, NCH, BB), dim3(256), 0, stream>>>(Kb, xb16, KXpb);
    k_red<<<dim3(BB * DD * CC / 8 / 256), dim3(256), 0, stream>>>(KXpb, KXb);
    k_kv<<<dim3(CC / 64, BB), dim3(256), 0, stream>>>(KXb, Wv, bv, Ksum, KVTb);
    k_out<<<dim3(2048), dim3(256), 0, stream>>>(xb16, Qb, KVTb, Ksum, gamma, out);
}